// Round 7
// baseline (134.189 us; speedup 1.0000x reference)
//
#include <hip/hip_runtime.h>

// MPS tensor-train classifier, B=16384, D=784, BOND=5, OUT=10.
//
// Round-10: HYBRID coefficient delivery. Three structures (r1 LDS-only,
// r7 SMEM-only, r9 SMEM+split) all land at ~47 us: each pushed all 25
// coefficient quads/pair through ONE pipe, and either pipe saturates at
// about the same rate (LDS: ~10.9k broadcast b128/CU; SMEM: 25 s_loads/
// pair vs 112-SGPR budget -> shallow prefetch, repeated lgkmcnt stalls).
// This round splits the 25 quads across BOTH pipes so they overlap:
//   - 10 quads (q0,q1 rows) preloaded ONCE per block into LDS (31.2 KB,
//     no staging in the loop, uniform broadcast ds_read_b128)
//   - 15 quads (q2,q3 rows + col4 + c44) via s_load (60 SGPRs transient)
// Topology = round-9 split (proven): 512 blocks x 1024 thr, block =
// {row-group g, half h}; wave 0 = vec chain (15 pairs + boundary),
// waves 1..15 = 12-pair matrix chains; combine now 3 phases x 5 slots
// (matbuf 32 KB) so static LDS = 63.2 KB < 64 KB, 2 blocks/CU.
// Stash vL/wR in out-flat halves; finish_dot + finish_out as r9.
//
// pk layout (100 floats/pair), q = 0..3 (coeff of 1, xa, xb, xa*xb):
//   rows:  q*20 + l*4 + r  -> quad s4[q*5+l]; LDS gets s4[0..9] (q=0,1),
//   SMEM keeps g4 = s4+10: q2 rows g4[0..4], q3 rows g4[5..9],
//   col4 (l-major) g4[10..13], c44 quad g4[14].

typedef float v4f __attribute__((ext_vector_type(4)));
typedef float v2f __attribute__((ext_vector_type(2)));

constexpr int Bn     = 16384;
constexpr int Dn     = 784;
constexpr int NOUT   = 10;
constexpr int NPAIR  = 390;   // pairs cover sites 1..780
constexpr int PVEC   = 15;    // vec-wave pairs per half
constexpr int PMAT   = 12;    // pairs per matrix wave (15 waves per half)
constexpr int RHP0   = 195;   // right half first pair
constexpr int BWD_P0 = 375;   // pairs >= this stored transposed (right vec)
constexpr int PAIR_F = 100;   // floats per pair block
constexpr int WROFF  = Bn * 5; // wR stash offset (floats) in out

__device__ __forceinline__ v4f splat4(float x) { v4f v = {x, x, x, x}; return v; }
__device__ __forceinline__ v4f fma4(v4f a, v4f b, v4f c) {
    return __builtin_elementwise_fma(a, b, c);
}

struct Frag { v4f r[5]; float c4[5]; };          // 5x5 running product

// T = M @ C; C built l-major from LDS quads lq[0..9] + global (SMEM) g4[0..14]
__device__ __forceinline__ void matstepH(const Frag& M, Frag& T,
                                         const v4f* __restrict__ lq,
                                         const float* __restrict__ g, v2f xc) {
    const float xa = xc[0], xb = xc[1], xab = xa * xb;
    const v4f va = splat4(xa), vb = splat4(xb), vp = splat4(xab);
    const v4f* g4 = (const v4f*)g;
#pragma unroll
    for (int l = 0; l < 5; ++l) {
        v4f crow = fma4(vp, g4[5 + l], fma4(vb, g4[l], fma4(va, lq[5 + l], lq[l])));
        v4f cq = (l < 4) ? g4[10 + l] : g4[14];
        float c4l = fmaf(xab, cq[3], fmaf(xb, cq[2], fmaf(xa, cq[1], cq[0])));
#pragma unroll
        for (int i = 0; i < 5; ++i) {
            float mil = (l < 4) ? M.r[i][l] : M.c4[i];
            if (l == 0) {
                T.r[i]  = splat4(mil) * crow;
                T.c4[i] = mil * c4l;
            } else {
                T.r[i]  = fma4(splat4(mil), crow, T.r[i]);
                T.c4[i] = fmaf(mil, c4l, T.c4[i]);
            }
        }
    }
}

// c' = c @ C, hybrid build
__device__ __forceinline__ void vecstepH(v4f& cv, float& c4,
                                         const v4f* __restrict__ lq,
                                         const float* __restrict__ g, v2f xc) {
    const float xa = xc[0], xb = xc[1], xab = xa * xb;
    const v4f va = splat4(xa), vb = splat4(xb), vp = splat4(xab);
    const v4f* g4 = (const v4f*)g;
    v4f acc; float a4;
#pragma unroll
    for (int l = 0; l < 5; ++l) {
        v4f crow = fma4(vp, g4[5 + l], fma4(vb, g4[l], fma4(va, lq[5 + l], lq[l])));
        v4f cq = (l < 4) ? g4[10 + l] : g4[14];
        float c4l = fmaf(xab, cq[3], fmaf(xb, cq[2], fmaf(xa, cq[1], cq[0])));
        float cl = (l < 4) ? cv[l] : c4;
        if (l == 0) { acc = splat4(cl) * crow; a4 = cl * c4l; }
        else        { acc = fma4(splat4(cl), crow, acc); a4 = fmaf(cl, c4l, a4); }
    }
    cv = acc; c4 = a4;
}

// ---- prepack: build pair blocks (transposed for p >= BWD_P0) ----
// cores_mid element (m,l,i,k) at (m*5+l)*10 + i*5 + k
__global__ void prepack_pairs(const float* __restrict__ cm, float* __restrict__ pk)
{
    int idx = blockIdx.x * 256 + threadIdx.x;
    if (idx >= NPAIR * 100) return;
    int p = idx / 100, rest = idx - p * 100;
    int q = rest / 25, e = rest - q * 25;
    int l = e / 5, r = e - l * 5;
    int m1 = 2 * p + 1, m2 = 2 * p + 2;
    const float* L = cm + (size_t)(m1 * 5 + l) * 10;
    float acc = 0.f;
#pragma unroll
    for (int k = 0; k < 5; ++k) {
        float Lk = (q & 1) ? (L[5 + k] - L[k]) : L[k];
        const float* R = cm + (size_t)(m2 * 5 + k) * 10;
        float Rk = (q & 2) ? (R[5 + r] - R[r]) : R[r];
        acc = fmaf(Lk, Rk, acc);
    }
    int wl = l, wr = r;
    if (p >= BWD_P0) { wl = r; wr = l; }   // store C^T for right vec wave
    int off;
    if (wr < 4)      off = q * 20 + wl * 4 + wr;
    else if (wl < 4) off = 80 + wl * 4 + q;   // col4, l-major
    else             off = 96 + q;            // c44 quad
    pk[(size_t)p * PAIR_F + off] = acc;
}

__global__ __launch_bounds__(1024, 4)
void mps_half_kernel(const float* __restrict__ x,          // [B, D]
                     const float* __restrict__ core_first, // [2,5]
                     const float* __restrict__ cores_mid,  // [782,5,2,5]
                     const float* __restrict__ core_last,  // [5,2]
                     const float* __restrict__ pk,         // [390][100]
                     float* __restrict__ out)              // [B,10] used as stash
{
    __shared__ v4f   pklds[195 * 10];     // 31.2 KB: q0,q1 quads, this half
    __shared__ float matbuf[5][25][64];   // 32.0 KB combine matrices

    const int lane = threadIdx.x & 63;
    const int wave = threadIdx.x >> 6;
    const int wu   = __builtin_amdgcn_readfirstlane(wave);  // uniform wave id
    const int g    = blockIdx.x >> 1;
    const int h    = blockIdx.x & 1;
    const int p0g  = (h == 0) ? 0 : RHP0;                   // half's first pair
    const int row  = g * 64 + lane;
    const float* __restrict__ xr = x + (size_t)row * Dn;
    const v2f* __restrict__ xr2 = (const v2f*)xr;          // 392 entries
    const v4f* __restrict__ pk4 = (const v4f*)pk;

    // ---- b0: cooperative preload of q0/q1 quads for this half ----
    for (int t = threadIdx.x; t < 195 * 10; t += 1024) {
        int pr = t / 10, q = t - pr * 10;
        pklds[t] = pk4[(size_t)(p0g + pr) * 25 + q];
    }
    __syncthreads();

    if (wu >= 1) {
        // ---- matrix wave: 12 pairs, hybrid LDS+SMEM coefficients ----
        const int p0 = p0g + PVEC + PMAT * (wu - 1);        // uniform

        Frag M, T;
        M.r[0] = {1,0,0,0}; M.r[1] = {0,1,0,0}; M.r[2] = {0,0,1,0};
        M.r[3] = {0,0,0,1}; M.r[4] = {0,0,0,0};
        M.c4[0] = 0; M.c4[1] = 0; M.c4[2] = 0; M.c4[3] = 0; M.c4[4] = 1;

        v2f x0 = xr2[p0 + 1], x1 = xr2[p0 + 2];
#pragma unroll 1
        for (int j = 0; j < PMAT; j += 2) {
            const v4f*  lq = pklds + (size_t)(p0 - p0g + j) * 10;
            const float* gm = pk + (size_t)(p0 + j) * PAIR_F + 40;
            v2f nx0 = xr2[p0 + j + 3], nx1 = xr2[p0 + j + 4];  // x prefetch
            matstepH(M, T, lq, gm, x0);
            matstepH(T, M, lq + 10, gm + PAIR_F, x1);
            x0 = nx0; x1 = nx1;
        }

        // slot phase/index: left vec consumes slots ascending (waves 1..15),
        // right vec descending (15..1); 3 phases of 5 slots.
        const int ord = (h == 0) ? (wu - 1) : (15 - wu);
        const int ph  = ord / 5;
        const int k   = ord - ph * 5;
        if (ph == 0) {
#pragma unroll
            for (int i = 0; i < 5; ++i) {
#pragma unroll
                for (int r = 0; r < 4; ++r) matbuf[k][i * 5 + r][lane] = M.r[i][r];
                matbuf[k][i * 5 + 4][lane] = M.c4[i];
            }
        }
        __syncthreads();   // b1: phase-0 slots ready
        __syncthreads();   // b2: vec finished reading phase-0
        if (ph == 1) {
#pragma unroll
            for (int i = 0; i < 5; ++i) {
#pragma unroll
                for (int r = 0; r < 4; ++r) matbuf[k][i * 5 + r][lane] = M.r[i][r];
                matbuf[k][i * 5 + 4][lane] = M.c4[i];
            }
        }
        __syncthreads();   // b3: phase-1 slots ready
        __syncthreads();   // b4: vec finished reading phase-1
        if (ph == 2) {
#pragma unroll
            for (int i = 0; i < 5; ++i) {
#pragma unroll
                for (int r = 0; r < 4; ++r) matbuf[k][i * 5 + r][lane] = M.r[i][r];
                matbuf[k][i * 5 + 4][lane] = M.c4[i];
            }
        }
        __syncthreads();   // b5: phase-2 slots ready
    } else if (h == 0) {
        // ---- left vec wave: carry0, site 0, pairs 0..14, combine asc ----
        v2f x01 = xr2[0];
        float cl[5], cn[5];
#pragma unroll
        for (int r = 0; r < 5; ++r)
            cl[r] = fmaf(x01[0], core_first[5 + r] - core_first[r], core_first[r]);
        const float* cm0 = cores_mid;                      // site 0
#pragma unroll
        for (int r = 0; r < 5; ++r) {
            float a = 0.f;
#pragma unroll
            for (int l = 0; l < 5; ++l) {
                float m = fmaf(x01[1], cm0[l * 10 + 5 + r] - cm0[l * 10 + r], cm0[l * 10 + r]);
                a = fmaf(cl[l], m, a);
            }
            cn[r] = a;
        }
        v4f cv = {cn[0], cn[1], cn[2], cn[3]};
        float c4 = cn[4];

        v2f xc = xr2[1];
#pragma unroll 1
        for (int p = 0; p < PVEC; ++p) {
            v2f nx = xr2[p + 2];
            vecstepH(cv, c4, pklds + (size_t)p * 10,
                     pk + (size_t)p * PAIR_F + 40, xc);
            xc = nx;
        }
        cl[0] = cv[0]; cl[1] = cv[1]; cl[2] = cv[2]; cl[3] = cv[3]; cl[4] = c4;

        __syncthreads();   // b1
#pragma unroll 1
        for (int k = 0; k < 5; ++k) {
            float v0[5];
#pragma unroll
            for (int r = 0; r < 5; ++r) v0[r] = cl[0] * matbuf[k][r][lane];
#pragma unroll
            for (int l = 1; l < 5; ++l)
#pragma unroll
                for (int r = 0; r < 5; ++r)
                    v0[r] = fmaf(cl[l], matbuf[k][l * 5 + r][lane], v0[r]);
#pragma unroll
            for (int r = 0; r < 5; ++r) cl[r] = v0[r];
        }
        __syncthreads();   // b2
        __syncthreads();   // b3
#pragma unroll 1
        for (int k = 0; k < 5; ++k) {
            float v0[5];
#pragma unroll
            for (int r = 0; r < 5; ++r) v0[r] = cl[0] * matbuf[k][r][lane];
#pragma unroll
            for (int l = 1; l < 5; ++l)
#pragma unroll
                for (int r = 0; r < 5; ++r)
                    v0[r] = fmaf(cl[l], matbuf[k][l * 5 + r][lane], v0[r]);
#pragma unroll
            for (int r = 0; r < 5; ++r) cl[r] = v0[r];
        }
        __syncthreads();   // b4
        __syncthreads();   // b5
#pragma unroll 1
        for (int k = 0; k < 5; ++k) {
            float v0[5];
#pragma unroll
            for (int r = 0; r < 5; ++r) v0[r] = cl[0] * matbuf[k][r][lane];
#pragma unroll
            for (int l = 1; l < 5; ++l)
#pragma unroll
                for (int r = 0; r < 5; ++r)
                    v0[r] = fmaf(cl[l], matbuf[k][l * 5 + r][lane], v0[r]);
#pragma unroll
            for (int r = 0; r < 5; ++r) cl[r] = v0[r];
        }
        float* o = out + (size_t)row * 5;                  // vL stash (flat)
#pragma unroll
        for (int i = 0; i < 5; ++i) o[i] = cl[i];
    } else {
        // ---- right vec wave: vlast, site 781, pairs 389..375 desc,
        //      combine desc (3 phases, column form) ----
        v2f xz = xr2[391];                                 // {x782, x783}
        float vl[5], vn[5];
#pragma unroll
        for (int l = 0; l < 5; ++l)
            vl[l] = fmaf(xz[1], core_last[2 * l + 1] - core_last[2 * l], core_last[2 * l]);
        const float* cmL = cores_mid + (size_t)781 * 50;
#pragma unroll
        for (int l = 0; l < 5; ++l) {
            float a = 0.f;
#pragma unroll
            for (int r = 0; r < 5; ++r) {
                float m = fmaf(xz[0], cmL[l * 10 + 5 + r] - cmL[l * 10 + r], cmL[l * 10 + r]);
                a = fmaf(m, vl[r], a);
            }
            vn[l] = a;
        }
        v4f cv = {vn[0], vn[1], vn[2], vn[3]};
        float c4 = vn[4];

        v2f xc = xr2[390];
#pragma unroll 1
        for (int p = 389; p >= BWD_P0; --p) {              // transposed storage
            v2f nx = xr2[p];                               // x for pair p-1
            vecstepH(cv, c4, pklds + (size_t)(p - RHP0) * 10,
                     pk + (size_t)p * PAIR_F + 40, xc);
            xc = nx;
        }
        float u[5] = {cv[0], cv[1], cv[2], cv[3], c4};

        __syncthreads();   // b1: waves 15..11 at k=0..4
#pragma unroll 1
        for (int k = 0; k < 5; ++k) {                      // u = M_slot @ u
            float v0[5];
#pragma unroll
            for (int i = 0; i < 5; ++i) {
                float a = matbuf[k][i * 5][lane] * u[0];
#pragma unroll
                for (int l = 1; l < 5; ++l)
                    a = fmaf(matbuf[k][i * 5 + l][lane], u[l], a);
                v0[i] = a;
            }
#pragma unroll
            for (int i = 0; i < 5; ++i) u[i] = v0[i];
        }
        __syncthreads();   // b2
        __syncthreads();   // b3: waves 10..6 at k=0..4
#pragma unroll 1
        for (int k = 0; k < 5; ++k) {
            float v0[5];
#pragma unroll
            for (int i = 0; i < 5; ++i) {
                float a = matbuf[k][i * 5][lane] * u[0];
#pragma unroll
                for (int l = 1; l < 5; ++l)
                    a = fmaf(matbuf[k][i * 5 + l][lane], u[l], a);
                v0[i] = a;
            }
#pragma unroll
            for (int i = 0; i < 5; ++i) u[i] = v0[i];
        }
        __syncthreads();   // b4
        __syncthreads();   // b5: waves 5..1 at k=0..4
#pragma unroll 1
        for (int k = 0; k < 5; ++k) {
            float v0[5];
#pragma unroll
            for (int i = 0; i < 5; ++i) {
                float a = matbuf[k][i * 5][lane] * u[0];
#pragma unroll
                for (int l = 1; l < 5; ++l)
                    a = fmaf(matbuf[k][i * 5 + l][lane], u[l], a);
                v0[i] = a;
            }
#pragma unroll
            for (int i = 0; i < 5; ++i) u[i] = v0[i];
        }
        float* o = out + WROFF + (size_t)row * 5;          // wR stash (flat)
#pragma unroll
        for (int i = 0; i < 5; ++i) o[i] = u[i];
    }
}

// ---- stage 2a: res[r] = vL . wR (res overwrites dead pk region of ws) ----
__global__ __launch_bounds__(256)
void finish_dot(const float* __restrict__ outF, float* __restrict__ res)
{
    int r = blockIdx.x * 256 + threadIdx.x;
    const float* vl = outF + (size_t)r * 5;
    const float* wr = outF + WROFF + (size_t)r * 5;
    float s = vl[0] * wr[0];
#pragma unroll
    for (int i = 1; i < 5; ++i) s = fmaf(vl[i], wr[i], s);
    res[r] = s;
}

// ---- stage 2b: out = res*fc_w + fc_b ----
__global__ __launch_bounds__(256)
void finish_out(const float* __restrict__ res, const float* __restrict__ fc_w,
                const float* __restrict__ fc_b, float* __restrict__ out)
{
    int r = blockIdx.x * 256 + threadIdx.x;
    float rv = res[r];
    float* o = out + (size_t)r * NOUT;
#pragma unroll
    for (int j = 0; j < NOUT; ++j) o[j] = fmaf(rv, fc_w[j], fc_b[j]);
}

extern "C" void kernel_launch(void* const* d_in, const int* in_sizes, int n_in,
                              void* d_out, int out_size, void* d_ws, size_t ws_size,
                              hipStream_t stream) {
    const float* x          = (const float*)d_in[0];
    const float* core_first = (const float*)d_in[1];
    const float* cores_mid  = (const float*)d_in[2];
    const float* core_last  = (const float*)d_in[3];
    const float* fc_w       = (const float*)d_in[4];
    const float* fc_b       = (const float*)d_in[5];
    float* out              = (float*)d_out;
    float* pk               = (float*)d_ws;   // 390*100*4 = 156,000 B
    float* res              = (float*)d_ws;   // reuses pk region (dead after main)

    hipLaunchKernelGGL(prepack_pairs, dim3((NPAIR * 100 + 255) / 256), dim3(256),
                       0, stream, cores_mid, pk);
    hipLaunchKernelGGL(mps_half_kernel, dim3(512), dim3(1024), 0, stream,
                       x, core_first, cores_mid, core_last, pk, out);
    hipLaunchKernelGGL(finish_dot, dim3(Bn / 256), dim3(256), 0, stream,
                       out, res);
    hipLaunchKernelGGL(finish_out, dim3(Bn / 256), dim3(256), 0, stream,
                       res, fc_w, fc_b, out);
}